// Round 6
// baseline (599.307 us; speedup 1.0000x reference)
//
#include <hip/hip_runtime.h>

#define BATCH   2
#define BEV_H   400
#define BEV_W   400
#define C_IN    128
#define C_OUT   256
#define NPTS    120000
#define HW_TOT  (BEV_H*BEV_W)        // 160000
#define NPOS    (BATCH*HW_TOT)       // 320000
#define BN_EPS  1e-5f

#define GRID_BYTES  ((size_t)NPOS * C_IN * 4)   // 163,840,000
#define MASK_OFF    GRID_BYTES
#define STATS_OFF   164160000ULL                // grid + mask, 256-aligned
#define GRAM_N      (C_IN*C_IN)                 // 16384
#define GC_N        (GRAM_N + C_IN)             // 16512

typedef __attribute__((ext_vector_type(8))) short bf16x8;
typedef __attribute__((ext_vector_type(4))) float f32x4;

// RTNE float->bf16 pack (inputs are finite; no NaN handling needed)
__device__ __forceinline__ unsigned pk2bf(float a, float b) {
  unsigned ua = __float_as_uint(a), ub = __float_as_uint(b);
  ua += 0x7fffu + ((ua >> 16) & 1u);
  ub += 0x7fffu + ((ub >> 16) & 1u);
  return (ua >> 16) | (ub & 0xffff0000u);
}

// ---------------- scatter-max (positive floats -> int atomicMax is exact) ----------------
__global__ __launch_bounds__(256)
void k_scatter(const float* __restrict__ feats, const int* __restrict__ coords,
               float* __restrict__ grid, unsigned char* __restrict__ mask)
{
  int i = blockIdx.x * 256 + threadIdx.x;
  if (i >= NPTS * C_IN) return;
  int p = i >> 7;
  int c = i & (C_IN - 1);
  int b = coords[p*4 + 0];
  int y = coords[p*4 + 2];
  int x = coords[p*4 + 3];
  size_t cell = (size_t)b * HW_TOT + (size_t)y * BEV_W + x;
  float f = feats[i];
  atomicMax((int*)(grid + cell * C_IN + c), __float_as_int(f));
  if (c == 0) mask[cell] = 1;
}

// ---------------- Gram matrix + column sums of grid (skip all-zero rows) ----------------
#define GR_BLOCKS 500
#define GR_ROWS   (NPOS / GR_BLOCKS)   // 640
#define RB        16

__global__ __launch_bounds__(256)
void k_gram(const float* __restrict__ grid, const unsigned char* __restrict__ mask,
            float* __restrict__ part)
{
  __shared__ float rows[RB][C_IN];
  __shared__ unsigned char sm[RB];
  const int tid = threadIdx.x;
  const int ti = tid >> 4, tj = tid & 15;
  float acc[8][8];
  #pragma unroll
  for (int i = 0; i < 8; ++i)
    #pragma unroll
    for (int j = 0; j < 8; ++j) acc[i][j] = 0.f;
  float csum[8];
  #pragma unroll
  for (int i = 0; i < 8; ++i) csum[i] = 0.f;

  const int r0 = blockIdx.x * GR_ROWS;
  const float4* g4 = (const float4*)grid;

  for (int rb = r0; rb < r0 + GR_ROWS; rb += RB) {
    float4* s4 = (float4*)&rows[0][0];
    s4[tid]       = g4[(size_t)rb*32 + tid];
    s4[tid + 256] = g4[(size_t)rb*32 + tid + 256];
    if (tid < RB) sm[tid] = mask[rb + tid];
    __syncthreads();
    #pragma unroll 1
    for (int rr = 0; rr < RB; ++rr) {
      if (!sm[rr]) continue;
      const float* row = rows[rr];
      float4 a0 = *(const float4*)(row + ti*8);
      float4 a1 = *(const float4*)(row + ti*8 + 4);
      float4 b0 = *(const float4*)(row + tj*8);
      float4 b1 = *(const float4*)(row + tj*8 + 4);
      float av[8] = {a0.x,a0.y,a0.z,a0.w,a1.x,a1.y,a1.z,a1.w};
      float bv[8] = {b0.x,b0.y,b0.z,b0.w,b1.x,b1.y,b1.z,b1.w};
      #pragma unroll
      for (int i = 0; i < 8; ++i)
        #pragma unroll
        for (int j = 0; j < 8; ++j) acc[i][j] = fmaf(av[i], bv[j], acc[i][j]);
      if (tj == 0) {
        #pragma unroll
        for (int i = 0; i < 8; ++i) csum[i] += av[i];
      }
    }
    __syncthreads();
  }

  float* my = part + (size_t)blockIdx.x * GC_N;
  #pragma unroll
  for (int i = 0; i < 8; ++i)
    #pragma unroll
    for (int j = 0; j < 8; ++j)
      my[(ti*8+i)*C_IN + tj*8+j] = acc[i][j];
  if (tj == 0) {
    #pragma unroll
    for (int i = 0; i < 8; ++i) my[GRAM_N + ti*8+i] = csum[i];
  }
}

// ---------------- reduce partials ----------------
__global__ __launch_bounds__(256)
void k_reduce(const float* __restrict__ part, float* __restrict__ stats)
{
  int j = blockIdx.x*256 + threadIdx.x;
  if (j >= GC_N) return;
  float s = 0.f;
  for (int b = 0; b < GR_BLOCKS; ++b) s += part[(size_t)b*GC_N + j];
  stats[j] = s;
}

// ---------------- per-channel BN scale/shift from Gram ----------------
__global__ __launch_bounds__(128)
void k_finalize(const float* __restrict__ stats, const float* __restrict__ convw,
                const float* __restrict__ gamma, const float* __restrict__ beta,
                float* __restrict__ scale_shift)
{
  const int o = blockIdx.x;
  const int t = threadIdx.x;
  const float* gram   = stats;
  const float* colsum = stats + GRAM_N;
  const float* wo = convw + o*C_IN;
  float wt = wo[t];
  float v = 0.f;
  #pragma unroll 4
  for (int c = 0; c < C_IN; ++c) v = fmaf(gram[t*C_IN + c], wo[c], v);
  float quad = wt * v;
  float ms   = wt * colsum[t];
  #pragma unroll
  for (int off = 32; off > 0; off >>= 1) {
    quad += __shfl_down(quad, off);
    ms   += __shfl_down(ms, off);
  }
  __shared__ float sq[2], sm2[2];
  if ((t & 63) == 0) { sq[t>>6] = quad; sm2[t>>6] = ms; }
  __syncthreads();
  if (t == 0) {
    float q = sq[0] + sq[1];
    float m = sm2[0] + sm2[1];
    float mean = m * (1.f / NPOS);
    float var  = q * (1.f / NPOS) - mean*mean;
    float rstd = rsqrtf(var + BN_EPS);
    float sc = gamma[o] * rstd;
    scale_shift[o]         = sc;
    scale_shift[C_OUT + o] = beta[o] - mean * sc;
  }
}

// ---------------- bf16 MFMA GEMM (BM=128, BN=256, K=128) + fused BN/ReLU ----------------
// A = grid rows (fp32 -> bf16), B = convw rows (convw[o][c] IS B^T: both K-contiguous).
// LDS XOR-swizzle: byte ^= (row&7)<<4  (row stride 256B would otherwise 16-way conflict).
__global__ __launch_bounds__(512)
void k_gemm(const float* __restrict__ grid, const float* __restrict__ convw,
            const float* __restrict__ scale_shift, float* __restrict__ out)
{
  __shared__ short lA[128*128];   // 32KB bf16
  __shared__ short lB[256*128];   // 64KB bf16

  const int tid  = threadIdx.x;
  const int lane = tid & 63;
  const int wid  = tid >> 6;      // 8 waves
  const int wm   = wid >> 2;      // 0..1 -> m-offset wm*64
  const int wo   = wid & 3;       // 0..3 -> o-offset wo*64
  const int m0   = blockIdx.x * 128;

  // ---- stage A: 128x128 fp32 -> bf16 LDS (each wave reads contiguous 1KB/instr) ----
  {
    const float4* g4 = (const float4*)(grid + (size_t)m0 * C_IN);
    #pragma unroll
    for (int p = 0; p < 8; ++p) {
      int f = p*512 + tid;          // float4 index, 0..4095
      int r = f >> 5;               // row 0..127
      int cb = (f & 31) * 8;        // bf16 byte offset of this float4
      float4 v = g4[f];
      uint2 w; w.x = pk2bf(v.x, v.y); w.y = pk2bf(v.z, v.w);
      *(uint2*)((char*)lA + r*256 + (cb ^ ((r & 7) << 4))) = w;
    }
  }
  // ---- stage B: 256x128 fp32 -> bf16 LDS ----
  {
    const float4* w4 = (const float4*)convw;
    #pragma unroll
    for (int p = 0; p < 16; ++p) {
      int f = p*512 + tid;          // 0..8191
      int r = f >> 5;               // row 0..255
      int cb = (f & 31) * 8;
      float4 v = w4[f];
      uint2 w; w.x = pk2bf(v.x, v.y); w.y = pk2bf(v.z, v.w);
      *(uint2*)((char*)lB + r*256 + (cb ^ ((r & 7) << 4))) = w;
    }
  }
  __syncthreads();

  f32x4 acc[4][4] = {};            // [mt][ot]
  const int lr = lane & 15;
  const int lg = lane >> 4;
  const int kb = lg << 4;          // lane's 16B k-slice offset within a 64B ks-chunk

  int arow[4], axr[4], brow[4], bxr[4];
  #pragma unroll
  for (int t = 0; t < 4; ++t) {
    int ra = wm*64 + t*16 + lr; arow[t] = ra*256; axr[t] = (ra & 7) << 4;
    int rb = wo*64 + t*16 + lr; brow[t] = rb*256; bxr[t] = (rb & 7) << 4;
  }

  #pragma unroll
  for (int ks = 0; ks < 4; ++ks) {
    bf16x8 af[4], bfr[4];
    #pragma unroll
    for (int t = 0; t < 4; ++t)
      af[t] = *(bf16x8*)((char*)lA + arow[t] + (((ks << 6) | kb) ^ axr[t]));
    #pragma unroll
    for (int t = 0; t < 4; ++t)
      bfr[t] = *(bf16x8*)((char*)lB + brow[t] + (((ks << 6) | kb) ^ bxr[t]));
    #pragma unroll
    for (int i = 0; i < 4; ++i)
      #pragma unroll
      for (int j = 0; j < 4; ++j)
        acc[i][j] = __builtin_amdgcn_mfma_f32_16x16x32_bf16(af[i], bfr[j], acc[i][j], 0, 0, 0);
  }

  // ---- epilogue: D[m][o], lane: o = tile + (lane&15), m = tile + (lane>>4)*4 + reg ----
  const int b      = m0 / HW_TOT;                      // 1250 blocks/batch exactly: never straddles
  const int hwbase = m0 - b*HW_TOT + wm*64 + (lg << 2);
  #pragma unroll
  for (int j = 0; j < 4; ++j) {
    int o = wo*64 + j*16 + lr;
    float sc = scale_shift[o];
    float sh = scale_shift[C_OUT + o];
    float* obase = out + ((size_t)(b*C_OUT + o)) * HW_TOT + hwbase;
    #pragma unroll
    for (int i = 0; i < 4; ++i) {
      float4 v;
      v.x = fmaxf(fmaf(acc[i][j][0], sc, sh), 0.f);
      v.y = fmaxf(fmaf(acc[i][j][1], sc, sh), 0.f);
      v.z = fmaxf(fmaf(acc[i][j][2], sc, sh), 0.f);
      v.w = fmaxf(fmaf(acc[i][j][3], sc, sh), 0.f);
      *(float4*)(obase + i*16) = v;
    }
  }
}

extern "C" void kernel_launch(void* const* d_in, const int* in_sizes, int n_in,
                              void* d_out, int out_size, void* d_ws, size_t ws_size,
                              hipStream_t stream)
{
  const float* feats  = (const float*)d_in[0];
  const int*   coords = (const int*)d_in[1];
  const float* convw  = (const float*)d_in[2];
  const float* gamma  = (const float*)d_in[3];
  const float* beta   = (const float*)d_in[4];
  float* out = (float*)d_out;

  float* grid = (float*)d_ws;
  unsigned char* mask = (unsigned char*)d_ws + MASK_OFF;
  float* stats = (float*)((char*)d_ws + STATS_OFF);   // GC_N floats
  float* scale_shift = stats + GC_N;                  // 512 floats
  float* part = out;  // reuse d_out as Gram-partials scratch (fully overwritten by k_gemm)

  hipMemsetAsync(d_ws, 0, STATS_OFF, stream);         // zero grid + mask
  k_scatter<<<(NPTS*C_IN + 255)/256, 256, 0, stream>>>(feats, coords, grid, mask);
  k_gram<<<GR_BLOCKS, 256, 0, stream>>>(grid, mask, part);
  k_reduce<<<(GC_N + 255)/256, 256, 0, stream>>>(part, stats);
  k_finalize<<<C_OUT, 128, 0, stream>>>(stats, convw, gamma, beta, scale_shift);
  k_gemm<<<NPOS/128, 512, 0, stream>>>(grid, convw, scale_shift, out);
}

// Round 9
// 582.707 us; speedup vs baseline: 1.0285x; 1.0285x over previous
//
#include <hip/hip_runtime.h>

#define BATCH   2
#define BEV_H   400
#define BEV_W   400
#define C_IN    128
#define C_OUT   256
#define NPTS    120000
#define HW_TOT  (BEV_H*BEV_W)        // 160000
#define NPOS    (BATCH*HW_TOT)       // 320000
#define BN_EPS  1e-5f

#define GRID_BYTES  ((size_t)NPOS * C_IN * 4)   // 163,840,000
#define MASK_OFF    GRID_BYTES
#define STATS_OFF   164160000ULL                // grid + mask, 256B-aligned
#define GRAM_N      (C_IN*C_IN)                 // 16384
#define GC_N        (GRAM_N + C_IN)             // 16512
#define BW_OFF      (STATS_OFF + (size_t)GC_N*4)      // 164226048, 256B-aligned
#define SS_OFF      (BW_OFF + (size_t)C_OUT*C_IN*2)   // 164291584

typedef __attribute__((ext_vector_type(8))) short bf16x8;
typedef __attribute__((ext_vector_type(4))) float f32x4;

// RTNE float->bf16 pack (inputs finite)
__device__ __forceinline__ unsigned pk2bf(float a, float b) {
  unsigned ua = __float_as_uint(a), ub = __float_as_uint(b);
  ua += 0x7fffu + ((ua >> 16) & 1u);
  ub += 0x7fffu + ((ub >> 16) & 1u);
  return (ua >> 16) | (ub & 0xffff0000u);
}

// ---------------- scatter-max (positive floats -> int atomicMax is exact) ----------------
__global__ __launch_bounds__(256)
void k_scatter(const float* __restrict__ feats, const int* __restrict__ coords,
               float* __restrict__ grid, unsigned char* __restrict__ mask)
{
  int i = blockIdx.x * 256 + threadIdx.x;
  if (i >= NPTS * C_IN) return;
  int p = i >> 7;
  int c = i & (C_IN - 1);
  int b = coords[p*4 + 0];
  int y = coords[p*4 + 2];
  int x = coords[p*4 + 3];
  size_t cell = (size_t)b * HW_TOT + (size_t)y * BEV_W + x;
  float f = feats[i];
  atomicMax((int*)(grid + cell * C_IN + c), __float_as_int(f));
  if (c == 0) mask[cell] = 1;
}

// ---------------- convw fp32 -> bf16 (run once per launch; L2-feeds k_gemm B) ----------------
__global__ __launch_bounds__(256)
void k_wcvt(const float* __restrict__ convw, unsigned* __restrict__ bw)
{
  int i = blockIdx.x*256 + threadIdx.x;      // 16384 float-pairs
  float2 v = ((const float2*)convw)[i];
  bw[i] = pk2bf(v.x, v.y);
}

// ---------------- Gram matrix + column sums of grid (skip all-zero rows) ----------------
#define GR_BLOCKS 500
#define GR_ROWS   (NPOS / GR_BLOCKS)   // 640
#define RB        16

__global__ __launch_bounds__(256)
void k_gram(const float* __restrict__ grid, const unsigned char* __restrict__ mask,
            float* __restrict__ part)
{
  __shared__ float rows[RB][C_IN];
  __shared__ unsigned char sm[RB];
  const int tid = threadIdx.x;
  const int ti = tid >> 4, tj = tid & 15;
  float acc[8][8];
  #pragma unroll
  for (int i = 0; i < 8; ++i)
    #pragma unroll
    for (int j = 0; j < 8; ++j) acc[i][j] = 0.f;
  float csum[8];
  #pragma unroll
  for (int i = 0; i < 8; ++i) csum[i] = 0.f;

  const int r0 = blockIdx.x * GR_ROWS;
  const float4* g4 = (const float4*)grid;

  for (int rb = r0; rb < r0 + GR_ROWS; rb += RB) {
    float4* s4 = (float4*)&rows[0][0];
    s4[tid]       = g4[(size_t)rb*32 + tid];
    s4[tid + 256] = g4[(size_t)rb*32 + tid + 256];
    if (tid < RB) sm[tid] = mask[rb + tid];
    __syncthreads();
    #pragma unroll 1
    for (int rr = 0; rr < RB; ++rr) {
      if (!sm[rr]) continue;
      const float* row = rows[rr];
      float4 a0 = *(const float4*)(row + ti*8);
      float4 a1 = *(const float4*)(row + ti*8 + 4);
      float4 b0 = *(const float4*)(row + tj*8);
      float4 b1 = *(const float4*)(row + tj*8 + 4);
      float av[8] = {a0.x,a0.y,a0.z,a0.w,a1.x,a1.y,a1.z,a1.w};
      float bv[8] = {b0.x,b0.y,b0.z,b0.w,b1.x,b1.y,b1.z,b1.w};
      #pragma unroll
      for (int i = 0; i < 8; ++i)
        #pragma unroll
        for (int j = 0; j < 8; ++j) acc[i][j] = fmaf(av[i], bv[j], acc[i][j]);
      if (tj == 0) {
        #pragma unroll
        for (int i = 0; i < 8; ++i) csum[i] += av[i];
      }
    }
    __syncthreads();
  }

  float* my = part + (size_t)blockIdx.x * GC_N;
  #pragma unroll
  for (int i = 0; i < 8; ++i)
    #pragma unroll
    for (int j = 0; j < 8; ++j)
      my[(ti*8+i)*C_IN + tj*8+j] = acc[i][j];
  if (tj == 0) {
    #pragma unroll
    for (int i = 0; i < 8; ++i) my[GRAM_N + ti*8+i] = csum[i];
  }
}

// ---------------- parallel reduce: 258x25 blocks, atomicAdd into zeroed stats ----------------
#define RED_BSPLIT 25
#define RED_BCHUNK (GR_BLOCKS / RED_BSPLIT)   // 20

__global__ __launch_bounds__(64)
void k_reduce(const float* __restrict__ part, float* __restrict__ stats)
{
  int j  = blockIdx.x*64 + threadIdx.x;       // < GC_N (258*64 = 16512 exactly)
  int b0 = blockIdx.y * RED_BCHUNK;
  float s = 0.f;
  #pragma unroll
  for (int b = 0; b < RED_BCHUNK; ++b) s += part[(size_t)(b0+b)*GC_N + j];
  atomicAdd(&stats[j], s);
}

// ---------------- per-channel BN scale/shift from Gram ----------------
__global__ __launch_bounds__(128)
void k_finalize(const float* __restrict__ stats, const float* __restrict__ convw,
                const float* __restrict__ gamma, const float* __restrict__ beta,
                float* __restrict__ scale_shift)
{
  const int o = blockIdx.x;
  const int t = threadIdx.x;
  const float* gram   = stats;
  const float* colsum = stats + GRAM_N;
  const float* wo = convw + o*C_IN;
  float wt = wo[t];
  float v = 0.f;
  #pragma unroll 4
  for (int c = 0; c < C_IN; ++c) v = fmaf(gram[t*C_IN + c], wo[c], v);
  float quad = wt * v;
  float ms   = wt * colsum[t];
  #pragma unroll
  for (int off = 32; off > 0; off >>= 1) {
    quad += __shfl_down(quad, off);
    ms   += __shfl_down(ms, off);
  }
  __shared__ float sq[2], sm2[2];
  if ((t & 63) == 0) { sq[t>>6] = quad; sm2[t>>6] = ms; }
  __syncthreads();
  if (t == 0) {
    float q = sq[0] + sq[1];
    float m = sm2[0] + sm2[1];
    float mean = m * (1.f / NPOS);
    float var  = q * (1.f / NPOS) - mean*mean;
    float rstd = rsqrtf(var + BN_EPS);
    float sc = gamma[o] * rstd;
    scale_shift[o]         = sc;
    scale_shift[C_OUT + o] = beta[o] - mean * sc;
  }
}

// ---------------- bf16 MFMA GEMM (BM=128, BN=256, K=128) + fused BN/ReLU ----------------
// A = grid rows (fp32 -> bf16 pack), B = pre-converted bf16 convw (row-major IS B^T).
// LDS XOR-swizzle: byte ^= (row&7)<<4  (row stride 256B would otherwise 16-way conflict).
__global__ __launch_bounds__(512)
void k_gemm(const float* __restrict__ grid, const uint4* __restrict__ bw,
            const float* __restrict__ scale_shift, float* __restrict__ out)
{
  __shared__ short lA[128*128];   // 32KB bf16
  __shared__ short lB[256*128];   // 64KB bf16

  const int tid  = threadIdx.x;
  const int lane = tid & 63;
  const int wid  = tid >> 6;      // 8 waves
  const int wm   = wid >> 2;      // 0..1 -> m-offset wm*64
  const int wo   = wid & 3;       // 0..3 -> o-offset wo*64
  const int m0   = blockIdx.x * 128;

  // ---- stage A: 128x128 fp32 -> bf16 LDS (4096 float4 chunks) ----
  {
    const float4* g4 = (const float4*)(grid + (size_t)m0 * C_IN);
    #pragma unroll
    for (int p = 0; p < 8; ++p) {
      int f = p*512 + tid;          // float4 index, 0..4095
      int r = f >> 5;               // row 0..127 (32 float4/row)
      int cb = (f & 31) * 8;        // bf16 byte offset of this float4
      float4 v = g4[f];
      uint2 w; w.x = pk2bf(v.x, v.y); w.y = pk2bf(v.z, v.w);
      *(uint2*)((char*)lA + r*256 + (cb ^ ((r & 7) << 4))) = w;
    }
  }
  // ---- stage B: 256x128 bf16 straight copy (4096 uint4 chunks = FULL 64KB) ----
  {
    #pragma unroll
    for (int p = 0; p < 8; ++p) {   // BUGFIX round 8: was p<4 (staged only rows 0..127)
      int f = p*512 + tid;          // 16B-chunk index, 0..4095
      int r = f >> 4;               // row 0..255 (16 chunks/row)
      int cb = (f & 15) * 16;
      *(uint4*)((char*)lB + r*256 + (cb ^ ((r & 7) << 4))) = bw[f];
    }
  }
  __syncthreads();

  f32x4 acc[4][4] = {};            // [mt][ot]
  const int lr = lane & 15;
  const int lg = lane >> 4;
  const int kb = lg << 4;          // lane's 16B k-slice offset within a 64B ks-chunk

  int arow[4], axr[4], brow[4], bxr[4];
  #pragma unroll
  for (int t = 0; t < 4; ++t) {
    int ra = wm*64 + t*16 + lr; arow[t] = ra*256; axr[t] = (ra & 7) << 4;
    int rb = wo*64 + t*16 + lr; brow[t] = rb*256; bxr[t] = (rb & 7) << 4;
  }

  #pragma unroll
  for (int ks = 0; ks < 4; ++ks) {
    bf16x8 af[4], bfr[4];
    #pragma unroll
    for (int t = 0; t < 4; ++t)
      af[t] = *(bf16x8*)((char*)lA + arow[t] + (((ks << 6) | kb) ^ axr[t]));
    #pragma unroll
    for (int t = 0; t < 4; ++t)
      bfr[t] = *(bf16x8*)((char*)lB + brow[t] + (((ks << 6) | kb) ^ bxr[t]));
    #pragma unroll
    for (int i = 0; i < 4; ++i)
      #pragma unroll
      for (int j = 0; j < 4; ++j)
        acc[i][j] = __builtin_amdgcn_mfma_f32_16x16x32_bf16(af[i], bfr[j], acc[i][j], 0, 0, 0);
  }

  // ---- epilogue: lane holds o = tile+(lane&15), m = tile+(lane>>4)*4+reg ----
  const int b      = m0 / HW_TOT;                      // 1250 blocks/batch exactly
  const int hwbase = m0 - b*HW_TOT + wm*64 + (lg << 2);
  #pragma unroll
  for (int j = 0; j < 4; ++j) {
    int o = wo*64 + j*16 + lr;
    float sc = scale_shift[o];
    float sh = scale_shift[C_OUT + o];
    float* obase = out + ((size_t)(b*C_OUT + o)) * HW_TOT + hwbase;
    #pragma unroll
    for (int i = 0; i < 4; ++i) {
      float4 v;
      v.x = fmaxf(fmaf(acc[i][j][0], sc, sh), 0.f);
      v.y = fmaxf(fmaf(acc[i][j][1], sc, sh), 0.f);
      v.z = fmaxf(fmaf(acc[i][j][2], sc, sh), 0.f);
      v.w = fmaxf(fmaf(acc[i][j][3], sc, sh), 0.f);
      *(float4*)(obase + i*16) = v;
    }
  }
}

extern "C" void kernel_launch(void* const* d_in, const int* in_sizes, int n_in,
                              void* d_out, int out_size, void* d_ws, size_t ws_size,
                              hipStream_t stream)
{
  const float* feats  = (const float*)d_in[0];
  const int*   coords = (const int*)d_in[1];
  const float* convw  = (const float*)d_in[2];
  const float* gamma  = (const float*)d_in[3];
  const float* beta   = (const float*)d_in[4];
  float* out = (float*)d_out;

  float* grid = (float*)d_ws;
  unsigned char* mask = (unsigned char*)d_ws + MASK_OFF;
  float* stats = (float*)((char*)d_ws + STATS_OFF);          // GC_N floats (zeroed)
  unsigned* bw = (unsigned*)((char*)d_ws + BW_OFF);          // bf16 convw
  float* scale_shift = (float*)((char*)d_ws + SS_OFF);       // 512 floats
  float* part = out;  // reuse d_out as Gram-partials scratch (fully overwritten by k_gemm)

  hipMemsetAsync(d_ws, 0, STATS_OFF + (size_t)GC_N*4, stream);  // zero grid+mask+stats
  k_scatter<<<(NPTS*C_IN + 255)/256, 256, 0, stream>>>(feats, coords, grid, mask);
  k_wcvt<<<(C_OUT*C_IN/2 + 255)/256, 256, 0, stream>>>(convw, bw);
  k_gram<<<GR_BLOCKS, 256, 0, stream>>>(grid, mask, part);
  k_reduce<<<dim3(GC_N/64, RED_BSPLIT), 64, 0, stream>>>(part, stats);
  k_finalize<<<C_OUT, 128, 0, stream>>>(stats, convw, gamma, beta, scale_shift);
  k_gemm<<<NPOS/128, 512, 0, stream>>>(grid, (const uint4*)bw, scale_shift, out);
}